// Round 11
// baseline (36.662 us; speedup 1.0000x reference)
//
#include <hip/hip_runtime.h>
#include <cmath>

constexpr int NN   = 1536;       // nodes
constexpr int FF   = 512;        // in features
constexpr int HH   = 64;         // hidden
constexpr int RPB  = 16;         // k_pre rows per block
constexpr int NBP  = NN / RPB;   // 96 pre blocks
constexpr int LRPB = 32;         // layer rows per block
constexpr int NBL  = NN / LRPB;  // 48 layer blocks
constexpr int NT   = 1024;       // 16 waves
constexpr int KST  = NN / 32;    // 48 k-steps
constexpr int KST1 = FF / 32;    // 16 k-steps for x@W1

// layer LDS union (bytes)
constexpr int O_RED  = 98304;   // 34816: [8][4][16][17] f32
constexpr int O_WNB  = 133120;  // 16384: 16 B-tiles x 512 u16
constexpr int O_XA   = 149504;  //  4096: x as A-tiles [2rt][2ks][512] u16
constexpr int O_XLOC = 153600;  //  8320: [32][65] f32
constexpr int LDS_L  = 161920;  // 158.1 KB -> 1 block/CU

using f32x4  = __attribute__((ext_vector_type(4))) float;
using bf16x8 = __attribute__((ext_vector_type(8))) short;
using u16x4  = __attribute__((ext_vector_type(4))) unsigned short;
typedef unsigned short u16;

__device__ __forceinline__ u16 f2bf(float f) {  // RNE fp32 -> bf16
  unsigned u = __builtin_bit_cast(unsigned, f);
  return (u16)((u + 0x7fffu + ((u >> 16) & 1u)) >> 16);
}

// B-tile index for a [1536 k x 64 c] matrix, column-half contiguous.
__device__ __forceinline__ size_t bidx(int k, int c) {
  return (size_t)((c >> 5) * (KST * 2) + (k >> 5) * 2 + ((c >> 4) & 1)) * 512 +
         ((k & 31) >> 3) * 128 + (c & 15) * 8 + (k & 7);
}

__device__ __forceinline__ void gl_lds16(const void* g, void* l) {
  __builtin_amdgcn_global_load_lds(
      (const __attribute__((address_space(1))) unsigned*)g,
      (__attribute__((address_space(3))) unsigned*)l, 16, 0, 0);
}

__device__ __forceinline__ void pack_wnb(u16* WnB, const float* Wsrc, int tid) {
  // Bmat[k][j'], k 0..63, j' 0..127; j'<64 -> Wn[k][j'], else Wn[64+k][j'-64]
  int jp = tid & 127, kb = (tid >> 7) * 8;
  int srow0 = (jp >> 6) * 64, col = jp & 63;
#pragma unroll
  for (int i = 0; i < 8; ++i) {
    int k = kb + i;
    WnB[((k >> 5) * 8 + (jp >> 4)) * 512 + ((k & 31) >> 3) * 128 +
        (jp & 15) * 8 + (k & 7)] = f2bf(Wsrc[(size_t)(srow0 + k) * HH + col]);
  }
}

// ---- k_pre: adj -> adjT A-tiles + deg; t1 = x@W1 (MFMA) -> t1T B-tiles ----
__global__ __launch_bounds__(NT, 4) void k_pre(
    const float* __restrict__ x, const float* __restrict__ adj,
    const float* __restrict__ W1,
    u16* __restrict__ adjT, u16* __restrict__ t1T, float* __restrict__ deg) {
  __shared__ u16 Al[KST1 * 512];        // 16 KB
  __shared__ u16 Bl[KST1 * 4 * 512];    // 64 KB
  __shared__ u16 Jl[KST * 512];         // 48 KB
  __shared__ float red0[4][4][16][16];  // 16 KB
  const int tid = threadIdx.x, lane = tid & 63, wave = tid >> 6;
  const int i0 = blockIdx.x * RPB;

  {  // pack x rows -> Al (wave = row, lane: 8 k)
    int j0 = lane * 8;
    const float* src = x + (size_t)(i0 + wave) * FF + j0;
    bf16x8 v;
#pragma unroll
    for (int jj = 0; jj < 8; ++jj) v[jj] = (short)f2bf(src[jj]);
    *(bf16x8*)&Al[(j0 >> 5) * 512 + ((j0 & 31) >> 3) * 128 + wave * 8] = v;
  }
  {  // pack W1 -> Bl (thread: one k-row, 32 cols)
    int k = tid >> 1, c0 = (tid & 1) * 32;
    const float* src = W1 + (size_t)k * HH + c0;
    int base = (k >> 5) * 2048 + ((k & 31) >> 3) * 128 + (k & 7);
#pragma unroll 8
    for (int cc = 0; cc < 32; ++cc) {
      int c = c0 + cc;
      Bl[base + (c >> 4) * 512 + (c & 15) * 8] = f2bf(src[cc]);
    }
  }
  {  // pack adj slab -> Jl + deg (wave = row, lane: 24 k)
    int j0 = lane * 24;
    const float* src = adj + (size_t)(i0 + wave) * NN + j0;
    float ds = 0.f;
#pragma unroll
    for (int g = 0; g < 3; ++g) {
      bf16x8 v;
#pragma unroll
      for (int jj = 0; jj < 8; ++jj) {
        float f = src[g * 8 + jj];
        ds += f;
        v[jj] = (short)f2bf(f);
      }
      int k = j0 + g * 8;
      *(bf16x8*)&Jl[(k >> 5) * 512 + ((k & 31) >> 3) * 128 + wave * 8] = v;
    }
#pragma unroll
    for (int off = 32; off; off >>= 1) ds += __shfl_xor(ds, off, 64);
    if (lane == 0) deg[i0 + wave] = ds;
  }
  __syncthreads();

  {  // Jl -> adjT (48 KB linear)
    const float4* srcv = (const float4*)Jl;
    float4* dstv = (float4*)(adjT + (size_t)blockIdx.x * KST * 512);
#pragma unroll
    for (int s = 0; s < 3; ++s) dstv[tid + s * NT] = srcv[tid + s * NT];
  }
  {  // MFMA: t1 = x @ W1. wave = (ks 0..3, cg 0..3)
    int ks = wave >> 2, cg = wave & 3;
    f32x4 acc = {0.f, 0.f, 0.f, 0.f};
#pragma unroll
    for (int s = 0; s < 4; ++s) {
      int t = ks * 4 + s;
      bf16x8 a = *(const bf16x8*)&Al[t * 512 + lane * 8];
      bf16x8 b = *(const bf16x8*)&Bl[(t * 4 + cg) * 512 + lane * 8];
      acc = __builtin_amdgcn_mfma_f32_16x16x32_bf16(a, b, acc, 0, 0, 0);
    }
#pragma unroll
    for (int q = 0; q < 4; ++q)
      red0[ks][cg][(lane >> 4) * 4 + q][lane & 15] = acc[q];
  }
  __syncthreads();
  {  // combine 4 k-segments, write t1T (column-half B-tiles)
    int r = wave, c = lane;
    float v = red0[0][c >> 4][r][c & 15] + red0[1][c >> 4][r][c & 15] +
              red0[2][c >> 4][r][c & 15] + red0[3][c >> 4][r][c & 15];
    t1T[bidx(i0 + r, c)] = f2bf(v);
  }
}

// ---- k_layer (32 rows/block): y = adj@T; quarter-dbuf gl_lds staging ----
// MODE 0: x = relu(y+b);          outA = x@Wn_top (f32), outBT = x@Wn_bot
// MODE 1: x = elu(Ain*deg+y+b);   outA/outBT as above
// MODE 2: x = Ain*deg+y+b;        out = log_softmax(x)
template <int MODE>
__global__ __launch_bounds__(NT, 4) void k_layer(
    const u16* __restrict__ adjT, const u16* __restrict__ TT,
    const float* __restrict__ Ain, const float* __restrict__ deg,
    const float* __restrict__ bias, const float* __restrict__ Wn,
    float* __restrict__ outA, u16* __restrict__ outBT,
    float* __restrict__ out) {
  __shared__ __attribute__((aligned(16))) char LB[LDS_L];
  float* red  = (float*)(LB + O_RED);
  u16*   WnB  = (u16*)(LB + O_WNB);
  u16*   xA   = (u16*)(LB + O_XA);
  float* xloc = (float*)(LB + O_XLOC);

  const int tid = threadIdx.x, lane = tid & 63, wave = tid >> 6;
  const int i0 = blockIdx.x * LRPB;

  // A fragments: 3 ksteps x 2 row-tiles (pre-slabs 2b, 2b+1)
  bf16x8 afr[3][2];
#pragma unroll
  for (int rt = 0; rt < 2; ++rt) {
    const u16* ja = adjT + (size_t)(2 * blockIdx.x + rt) * (KST * 512);
#pragma unroll
    for (int s = 0; s < 3; ++s)
      afr[s][rt] = *(const bf16x8*)(ja + (wave * 3 + s) * 512 + lane * 8);
  }
  if (MODE < 2) pack_wnb(WnB, Wn, tid);

  char* const regA = LB + wave * 6144;   // 3 KB quarter buffers, per-wave
  char* const regB = regA + 3072;
  const int kb = wave * 3;
  const char* tb = (const char*)TT + (size_t)lane * 16;

  f32x4 acc[4][2] = {};
  // issue Q0 -> regA, Q1 -> regB  (quarter q covers col-group cg=q)
#pragma unroll
  for (int s = 0; s < 3; ++s)
    gl_lds16(tb + (size_t)((kb + s) * 2 + 0) * 1024, regA + s * 1024);
#pragma unroll
  for (int s = 0; s < 3; ++s)
    gl_lds16(tb + (size_t)((kb + s) * 2 + 1) * 1024, regB + s * 1024);

#pragma unroll
  for (int cg = 0; cg < 4; ++cg) {
    if (cg < 3) asm volatile("s_waitcnt vmcnt(3)" ::: "memory");
    else        asm volatile("s_waitcnt vmcnt(0)" ::: "memory");
    __builtin_amdgcn_sched_barrier(0);
    char* reg = (cg & 1) ? regB : regA;
    bf16x8 b0 = *(const bf16x8*)(reg);
    bf16x8 b1 = *(const bf16x8*)(reg + 1024);
    bf16x8 b2 = *(const bf16x8*)(reg + 2048);
    asm volatile("s_waitcnt lgkmcnt(0)" ::: "memory");
    __builtin_amdgcn_sched_barrier(0);
    if (cg < 2) {  // refill just-consumed region with quarter cg+2
      int q = cg + 2;
#pragma unroll
      for (int s = 0; s < 3; ++s)
        gl_lds16(tb + (size_t)((q >> 1) * 96 + (kb + s) * 2 + (q & 1)) * 1024,
                 reg + s * 1024);
    }
#pragma unroll
    for (int rt = 0; rt < 2; ++rt) {
      acc[cg][rt] = __builtin_amdgcn_mfma_f32_16x16x32_bf16(afr[0][rt], b0, acc[cg][rt], 0, 0, 0);
      acc[cg][rt] = __builtin_amdgcn_mfma_f32_16x16x32_bf16(afr[1][rt], b1, acc[cg][rt], 0, 0, 0);
      acc[cg][rt] = __builtin_amdgcn_mfma_f32_16x16x32_bf16(afr[2][rt], b2, acc[cg][rt], 0, 0, 0);
    }
  }

  // ---- reduction: two 16-row rounds over the shared padded red ----
#pragma unroll
  for (int rt = 0; rt < 2; ++rt) {
    if (rt == 1) __syncthreads();  // round-0 combine done before overwrite
    if (wave < 8) {
#pragma unroll
      for (int cg = 0; cg < 4; ++cg)
#pragma unroll
        for (int q = 0; q < 4; ++q)
          red[((wave * 4 + cg) * 16 + ((lane >> 4) * 4 + q)) * 17 +
              (lane & 15)] = acc[cg][rt][q];
    }
    __syncthreads();
    if (wave >= 8) {
#pragma unroll
      for (int cg = 0; cg < 4; ++cg)
#pragma unroll
        for (int q = 0; q < 4; ++q)
          red[(((wave - 8) * 4 + cg) * 16 + ((lane >> 4) * 4 + q)) * 17 +
              (lane & 15)] += acc[cg][rt][q];
    }
    __syncthreads();
    {  // combine 8 segments + bias + deg term + activation (row = rt*16+wave)
      int r = rt * 16 + wave;
      float v = bias[lane];
#pragma unroll
      for (int s = 0; s < 8; ++s)
        v += red[((s * 4 + (lane >> 4)) * 16 + wave) * 17 + (lane & 15)];
      if (MODE >= 1) v += Ain[(size_t)(i0 + r) * HH + lane] * deg[i0 + r];
      if (MODE == 0) v = fmaxf(v, 0.f);
      if (MODE == 1) v = v > 0.f ? v : expm1f(v);
      xloc[r * 65 + lane] = v;
      if (MODE < 2)
        xA[(rt * 2 + (lane >> 5)) * 512 + ((lane & 31) >> 3) * 128 + wave * 8 +
           (lane & 7)] = f2bf(v);
    }
  }
  __syncthreads();

  if (MODE < 2) {
    // epilogue: 16 waves = (rt, cgg); C = 32 x 128 via MFMA
    int rt = wave >> 3, cgg = wave & 7;
    f32x4 a2 = {};
#pragma unroll
    for (int s = 0; s < 2; ++s) {
      bf16x8 a = *(const bf16x8*)&xA[(rt * 2 + s) * 512 + lane * 8];
      bf16x8 b = *(const bf16x8*)&WnB[(s * 8 + cgg) * 512 + lane * 8];
      a2 = __builtin_amdgcn_mfma_f32_16x16x32_bf16(a, b, a2, 0, 0, 0);
    }
    int row0 = (lane >> 4) * 4, colg = lane & 15;
    if (cgg < 4) {
      int c = cgg * 16 + colg;
#pragma unroll
      for (int q = 0; q < 4; ++q)
        outA[(size_t)(i0 + rt * 16 + row0 + q) * HH + c] = a2[q];
    } else {
      int c = (cgg - 4) * 16 + colg;
      u16x4 v;
#pragma unroll
      for (int q = 0; q < 4; ++q) v[q] = f2bf(a2[q]);
      *(u16x4*)&outBT[bidx(i0 + rt * 16 + row0, c)] = v;
    }
  } else {
    // log_softmax: wave handles rows wave and wave+16
#pragma unroll
    for (int rr = 0; rr < 2; ++rr) {
      int r = wave + rr * 16;
      float v = xloc[r * 65 + lane];
      float m = v;
#pragma unroll
      for (int off = 32; off; off >>= 1) m = fmaxf(m, __shfl_xor(m, off, 64));
      float e = expf(v - m);
      float ssum = e;
#pragma unroll
      for (int off = 32; off; off >>= 1) ssum += __shfl_xor(ssum, off, 64);
      out[(size_t)(i0 + r) * HH + lane] = v - m - logf(ssum);
    }
  }
}

extern "C" void kernel_launch(void* const* d_in, const int* in_sizes, int n_in,
                              void* d_out, int out_size, void* d_ws,
                              size_t ws_size, hipStream_t stream) {
  const float* x   = (const float*)d_in[0];
  const float* adj = (const float*)d_in[2];  // adj1; d_in[1]/[3] are dead
  const float* W1  = (const float*)d_in[4];
  const float* b1  = (const float*)d_in[5];
  const float* W2  = (const float*)d_in[6];
  const float* b2  = (const float*)d_in[7];
  const float* W3  = (const float*)d_in[8];
  const float* b3  = (const float*)d_in[9];
  float* out = (float*)d_out;

  char* ws = (char*)d_ws;
  u16* adjT = (u16*)ws;                   // 4,718,592 B
  u16* t1T  = (u16*)(ws + 4718592);       // 196,608 B each (2 x 96KB halves)
  u16* B2T  = (u16*)(ws + 4915200);
  u16* B3T  = (u16*)(ws + 5111808);
  float* A2 = (float*)(ws + 5308416);     // 393,216 B each
  float* A3 = (float*)(ws + 5701632);
  float* dg = (float*)(ws + 6094848);     // 6,144 B

  k_pre<<<NBP, NT, 0, stream>>>(x, adj, W1, adjT, t1T, dg);
  k_layer<0><<<NBL, NT, 0, stream>>>(adjT, t1T, nullptr, nullptr, b1, W2, A2,
                                     B2T, nullptr);
  k_layer<1><<<NBL, NT, 0, stream>>>(adjT, B2T, A2, dg, b2, W3, A3, B3T,
                                     nullptr);
  k_layer<2><<<NBL, NT, 0, stream>>>(adjT, B3T, A3, dg, b3, nullptr, nullptr,
                                     nullptr, out);
}

// Round 12
// 30.092 us; speedup vs baseline: 1.2183x; 1.2183x over previous
//
#include <hip/hip_runtime.h>
#include <cmath>

constexpr int NN   = 1536;      // nodes
constexpr int FF   = 512;       // in features
constexpr int HH   = 64;        // hidden
constexpr int RPB  = 16;        // rows per block
constexpr int NB   = NN / RPB;  // 96 blocks
constexpr int NT   = 1024;      // 16 waves
constexpr int KST  = NN / 32;   // 48 k-steps
constexpr int KST1 = FF / 32;   // 16 k-steps for x@W1

using f32x4  = __attribute__((ext_vector_type(4))) float;
using bf16x8 = __attribute__((ext_vector_type(8))) short;
using u16x4  = __attribute__((ext_vector_type(4))) unsigned short;
typedef unsigned short u16;

__device__ __forceinline__ u16 f2bf(float f) {  // RNE fp32 -> bf16
  unsigned u = __builtin_bit_cast(unsigned, f);
  return (u16)((u + 0x7fffu + ((u >> 16) & 1u)) >> 16);
}

// B-tile index for a [1536 k x 64 c] matrix, column-half contiguous:
// half (c>>5) spans a contiguous 96KB; within it, tile = kstep*2 + ((c>>4)&1).
__device__ __forceinline__ size_t bidx(int k, int c) {
  return (size_t)((c >> 5) * (KST * 2) + (k >> 5) * 2 + ((c >> 4) & 1)) * 512 +
         ((k & 31) >> 3) * 128 + (c & 15) * 8 + (k & 7);
}

__device__ __forceinline__ void gl_lds16(const void* g, void* l) {
  __builtin_amdgcn_global_load_lds(
      (const __attribute__((address_space(1))) unsigned*)g,
      (__attribute__((address_space(3))) unsigned*)l, 16, 0, 0);
}

__device__ __forceinline__ void pack_wnb(u16* WnB, const float* Wsrc, int tid) {
  // Bmat[k][j'], k 0..63, j' 0..127; j'<64 -> Wn[k][j'], else Wn[64+k][j'-64]
  int jp = tid & 127, kb = (tid >> 7) * 8;
  int srow0 = (jp >> 6) * 64, col = jp & 63;
#pragma unroll
  for (int i = 0; i < 8; ++i) {
    int k = kb + i;
    WnB[((k >> 5) * 8 + (jp >> 4)) * 512 + ((k & 31) >> 3) * 128 +
        (jp & 15) * 8 + (k & 7)] = f2bf(Wsrc[(size_t)(srow0 + k) * HH + col]);
  }
}

// ---- k_pre: adj -> adjT A-tiles + deg; t1 = x@W1 (MFMA) -> t1T B-tiles ----
__global__ __launch_bounds__(NT, 4) void k_pre(
    const float* __restrict__ x, const float* __restrict__ adj,
    const float* __restrict__ W1,
    u16* __restrict__ adjT, u16* __restrict__ t1T, float* __restrict__ deg) {
  __shared__ u16 Al[KST1 * 512];        // 16 KB
  __shared__ u16 Bl[KST1 * 4 * 512];    // 64 KB
  __shared__ u16 Jl[KST * 512];         // 48 KB
  __shared__ float red0[4][4][16][16];  // 16 KB
  const int tid = threadIdx.x, lane = tid & 63, wave = tid >> 6;
  const int i0 = blockIdx.x * RPB;

  {  // pack x rows -> Al (wave = row, lane: 8 k) -- float4 loads
    int j0 = lane * 8;
    const float4* src = (const float4*)(x + (size_t)(i0 + wave) * FF + j0);
    float4 f0 = src[0], f1 = src[1];
    bf16x8 v;
    v[0] = (short)f2bf(f0.x); v[1] = (short)f2bf(f0.y);
    v[2] = (short)f2bf(f0.z); v[3] = (short)f2bf(f0.w);
    v[4] = (short)f2bf(f1.x); v[5] = (short)f2bf(f1.y);
    v[6] = (short)f2bf(f1.z); v[7] = (short)f2bf(f1.w);
    *(bf16x8*)&Al[(j0 >> 5) * 512 + ((j0 & 31) >> 3) * 128 + wave * 8] = v;
  }
  {  // pack W1 -> Bl (thread: one k-row, 32 cols) -- float4 loads
    int k = tid >> 1, c0 = (tid & 1) * 32;
    const float4* src = (const float4*)(W1 + (size_t)k * HH + c0);
    int base = (k >> 5) * 2048 + ((k & 31) >> 3) * 128 + (k & 7);
#pragma unroll
    for (int g = 0; g < 8; ++g) {
      float4 f = src[g];
      int c = c0 + g * 4;
      int off = base + (c >> 4) * 512 + (c & 15) * 8;
      Bl[off]      = f2bf(f.x);
      Bl[off + 8]  = f2bf(f.y);
      Bl[off + 16] = f2bf(f.z);
      Bl[off + 24] = f2bf(f.w);
    }
  }
  {  // pack adj slab -> Jl + deg (wave = row, lane: 24 k) -- float4 loads
    int j0 = lane * 24;
    const float4* src = (const float4*)(adj + (size_t)(i0 + wave) * NN + j0);
    float4 f[6];
#pragma unroll
    for (int g = 0; g < 6; ++g) f[g] = src[g];
    float ds = 0.f;
#pragma unroll
    for (int g = 0; g < 6; ++g) ds += f[g].x + f[g].y + f[g].z + f[g].w;
#pragma unroll
    for (int g = 0; g < 3; ++g) {
      bf16x8 v;
      v[0] = (short)f2bf(f[g * 2].x);     v[1] = (short)f2bf(f[g * 2].y);
      v[2] = (short)f2bf(f[g * 2].z);     v[3] = (short)f2bf(f[g * 2].w);
      v[4] = (short)f2bf(f[g * 2 + 1].x); v[5] = (short)f2bf(f[g * 2 + 1].y);
      v[6] = (short)f2bf(f[g * 2 + 1].z); v[7] = (short)f2bf(f[g * 2 + 1].w);
      int k = j0 + g * 8;
      *(bf16x8*)&Jl[(k >> 5) * 512 + ((k & 31) >> 3) * 128 + wave * 8] = v;
    }
#pragma unroll
    for (int off = 32; off; off >>= 1) ds += __shfl_xor(ds, off, 64);
    if (lane == 0) deg[i0 + wave] = ds;
  }
  __syncthreads();

  {  // Jl -> adjT (48 KB linear)
    const float4* srcv = (const float4*)Jl;
    float4* dstv = (float4*)(adjT + (size_t)blockIdx.x * KST * 512);
#pragma unroll
    for (int s = 0; s < 3; ++s) dstv[tid + s * NT] = srcv[tid + s * NT];
  }
  {  // MFMA: t1 = x @ W1. wave = (ks 0..3, cg 0..3)
    int ks = wave >> 2, cg = wave & 3;
    f32x4 acc = {0.f, 0.f, 0.f, 0.f};
#pragma unroll
    for (int s = 0; s < 4; ++s) {
      int t = ks * 4 + s;
      bf16x8 a = *(const bf16x8*)&Al[t * 512 + lane * 8];
      bf16x8 b = *(const bf16x8*)&Bl[(t * 4 + cg) * 512 + lane * 8];
      acc = __builtin_amdgcn_mfma_f32_16x16x32_bf16(a, b, acc, 0, 0, 0);
    }
#pragma unroll
    for (int q = 0; q < 4; ++q)
      red0[ks][cg][(lane >> 4) * 4 + q][lane & 15] = acc[q];
  }
  __syncthreads();
  {  // combine 4 k-segments, write t1T (column-half B-tiles)
    int r = wave, c = lane;
    float v = red0[0][c >> 4][r][c & 15] + red0[1][c >> 4][r][c & 15] +
              red0[2][c >> 4][r][c & 15] + red0[3][c >> 4][r][c & 15];
    t1T[bidx(i0 + r, c)] = f2bf(v);
  }
}

// ---- k_layer: y = adj@T via MFMA; quarter-dbuf gl_lds staging, 96 blocks ----
// MODE 0: x = relu(y+b);          outA = x@Wn_top (f32), outBT = x@Wn_bot
// MODE 1: x = elu(Ain*deg+y+b);   outA/outBT as above
// MODE 2: x = Ain*deg+y+b;        out = log_softmax(x)
template <int MODE>
__global__ __launch_bounds__(NT, 4) void k_layer(
    const u16* __restrict__ adjT, const u16* __restrict__ TT,
    const float* __restrict__ Ain, const float* __restrict__ deg,
    const float* __restrict__ bias, const float* __restrict__ Wn,
    float* __restrict__ outA, u16* __restrict__ outBT,
    float* __restrict__ out) {
  // LDS union (bytes): staging [16 waves][6144] @0, red8 @98304 (34816),
  // WnB @133120 (16384), xA @149504 (2048), xloc @151552 (4160) -> 155712 B
  __shared__ __attribute__((aligned(16))) char LB[155712];
  float* red8 = (float*)(LB + 98304);  // [8][4][16][17]
  u16*   WnB  = (u16*)(LB + 133120);   // 16 tiles x 512 u16
  u16*   xA   = (u16*)(LB + 149504);   // x as A-tiles [2][512]
  float* xloc = (float*)(LB + 151552); // [16][65]

  const int tid = threadIdx.x, lane = tid & 63, wave = tid >> 6;
  const int i0 = blockIdx.x * RPB;

  // adj A-fragments: 3 coalesced b128 loads
  const u16* ja = adjT + (size_t)blockIdx.x * (KST * 512);
  bf16x8 afr[3];
#pragma unroll
  for (int s = 0; s < 3; ++s)
    afr[s] = *(const bf16x8*)(ja + (wave * 3 + s) * 512 + lane * 8);

  if (MODE < 2) pack_wnb(WnB, Wn, tid);
  float dg = 0.f;
  if (MODE >= 1) dg = deg[i0 + wave];

  // quarter-dbuf staging: quarter q = col-group q, 3 tiles of 1KB.
  // tile byte offset: ((q>>1)*96 + (kb+s)*2 + (q&1)) * 1024
  char* const regA = LB + wave * 6144;
  char* const regB = regA + 3072;
  const int kb = wave * 3;
  const char* tb = (const char*)TT + (size_t)lane * 16;

  f32x4 acc[4] = {};
#pragma unroll
  for (int s = 0; s < 3; ++s)
    gl_lds16(tb + (size_t)((kb + s) * 2 + 0) * 1024, regA + s * 1024);
#pragma unroll
  for (int s = 0; s < 3; ++s)
    gl_lds16(tb + (size_t)((kb + s) * 2 + 1) * 1024, regB + s * 1024);

#pragma unroll
  for (int cg = 0; cg < 4; ++cg) {
    if (cg < 3) asm volatile("s_waitcnt vmcnt(3)" ::: "memory");
    else        asm volatile("s_waitcnt vmcnt(0)" ::: "memory");
    __builtin_amdgcn_sched_barrier(0);
    char* reg = (cg & 1) ? regB : regA;
    bf16x8 b0 = *(const bf16x8*)(reg);
    bf16x8 b1 = *(const bf16x8*)(reg + 1024);
    bf16x8 b2 = *(const bf16x8*)(reg + 2048);
    asm volatile("s_waitcnt lgkmcnt(0)" ::: "memory");
    __builtin_amdgcn_sched_barrier(0);
    if (cg < 2) {  // refill just-consumed region with quarter cg+2
      int q = cg + 2;
#pragma unroll
      for (int s = 0; s < 3; ++s)
        gl_lds16(tb + (size_t)((q >> 1) * 96 + (kb + s) * 2 + (q & 1)) * 1024,
                 reg + s * 1024);
    }
    acc[cg] = __builtin_amdgcn_mfma_f32_16x16x32_bf16(afr[0], b0, acc[cg], 0, 0, 0);
    acc[cg] = __builtin_amdgcn_mfma_f32_16x16x32_bf16(afr[1], b1, acc[cg], 0, 0, 0);
    acc[cg] = __builtin_amdgcn_mfma_f32_16x16x32_bf16(afr[2], b2, acc[cg], 0, 0, 0);
  }

  // 8-wave reduction tree (padded stride 17)
  if (wave < 8) {
#pragma unroll
    for (int cg = 0; cg < 4; ++cg)
#pragma unroll
      for (int q = 0; q < 4; ++q)
        red8[((wave * 4 + cg) * 16 + ((lane >> 4) * 4 + q)) * 17 +
             (lane & 15)] = acc[cg][q];
  }
  __syncthreads();
  if (wave >= 8) {
#pragma unroll
    for (int cg = 0; cg < 4; ++cg)
#pragma unroll
      for (int q = 0; q < 4; ++q)
        red8[(((wave - 8) * 4 + cg) * 16 + ((lane >> 4) * 4 + q)) * 17 +
             (lane & 15)] += acc[cg][q];
  }
  __syncthreads();

  {  // combine 8 segments + bias + deg term + activation
    float v = bias[lane];
#pragma unroll
    for (int s = 0; s < 8; ++s)
      v += red8[((s * 4 + (lane >> 4)) * 16 + wave) * 17 + (lane & 15)];
    if (MODE >= 1) v += Ain[(size_t)(i0 + wave) * HH + lane] * dg;
    if (MODE == 0) v = fmaxf(v, 0.f);
    if (MODE == 1) v = v > 0.f ? v : expm1f(v);
    xloc[wave * 65 + lane] = v;
    if (MODE < 2)
      xA[(lane >> 5) * 512 + ((lane & 31) >> 3) * 128 + wave * 8 +
         (lane & 7)] = f2bf(v);
  }
  __syncthreads();

  if (MODE < 2) {
    // epilogue: [outA | outBT] = x @ [Wn_top | Wn_bot] via MFMA (8 waves)
    if (wave < 8) {
      f32x4 a2 = {};
#pragma unroll
      for (int s = 0; s < 2; ++s) {
        bf16x8 a = *(const bf16x8*)&xA[s * 512 + lane * 8];
        bf16x8 b = *(const bf16x8*)&WnB[(s * 8 + wave) * 512 + lane * 8];
        a2 = __builtin_amdgcn_mfma_f32_16x16x32_bf16(a, b, a2, 0, 0, 0);
      }
      int row = (lane >> 4) * 4, colg = lane & 15;
      if (wave < 4) {
        int c = wave * 16 + colg;
#pragma unroll
        for (int q = 0; q < 4; ++q)
          outA[(size_t)(i0 + row + q) * HH + c] = a2[q];
      } else {
        int c = (wave - 4) * 16 + colg;
        u16x4 v;
#pragma unroll
        for (int q = 0; q < 4; ++q) v[q] = f2bf(a2[q]);
        *(u16x4*)&outBT[bidx(i0 + row, c)] = v;  // 4 consecutive k slots
      }
    }
  } else {
    // log_softmax: wave = row
    float v = xloc[wave * 65 + lane];
    float m = v;
#pragma unroll
    for (int off = 32; off; off >>= 1) m = fmaxf(m, __shfl_xor(m, off, 64));
    float e = expf(v - m);
    float ssum = e;
#pragma unroll
    for (int off = 32; off; off >>= 1) ssum += __shfl_xor(ssum, off, 64);
    out[(size_t)(i0 + wave) * HH + lane] = v - m - logf(ssum);
  }
}

extern "C" void kernel_launch(void* const* d_in, const int* in_sizes, int n_in,
                              void* d_out, int out_size, void* d_ws,
                              size_t ws_size, hipStream_t stream) {
  const float* x   = (const float*)d_in[0];
  const float* adj = (const float*)d_in[2];  // adj1; d_in[1]/[3] are dead
  const float* W1  = (const float*)d_in[4];
  const float* b1  = (const float*)d_in[5];
  const float* W2  = (const float*)d_in[6];
  const float* b2  = (const float*)d_in[7];
  const float* W3  = (const float*)d_in[8];
  const float* b3  = (const float*)d_in[9];
  float* out = (float*)d_out;

  char* ws = (char*)d_ws;
  u16* adjT = (u16*)ws;                   // 4,718,592 B
  u16* t1T  = (u16*)(ws + 4718592);       // 196,608 B each (2 x 96KB halves)
  u16* B2T  = (u16*)(ws + 4915200);
  u16* B3T  = (u16*)(ws + 5111808);
  float* A2 = (float*)(ws + 5308416);     // 393,216 B each
  float* A3 = (float*)(ws + 5701632);
  float* dg = (float*)(ws + 6094848);     // 6,144 B

  k_pre<<<NB, NT, 0, stream>>>(x, adj, W1, adjT, t1T, dg);
  k_layer<0><<<NB, NT, 0, stream>>>(adjT, t1T, nullptr, nullptr, b1, W2, A2,
                                    B2T, nullptr);
  k_layer<1><<<NB, NT, 0, stream>>>(adjT, B2T, A2, dg, b2, W3, A3, B3T,
                                    nullptr);
  k_layer<2><<<NB, NT, 0, stream>>>(adjT, B3T, A3, dg, b3, nullptr, nullptr,
                                    nullptr, out);
}